// Round 4
// baseline (16.603 us; speedup 1.0000x reference)
//
#include <hip/hip_runtime.h>

// Analytic collapse of the quantum circuit:
//   z = [cos(a)cos(b)*(S00 - S11) - 2*sin(a)*S01] / (S00 + S11)
// with a = ry0[0]+ry1[0], b = rx0[0],
//   S00 = sum(x[0:512]^2), S11 = sum(x[512:1024]^2), S01 = sum(x[0:512]*x[512:1024])
// Output: z replicated 16x per sample.
//
// R3: 4 samples/wave, one sample per 16-lane group -> 4-step butterfly
// (2 shfl/sample vs 12), single fully-coalesced 256B store per wave.
// Regular (cached) loads: x (64 MB) is L3-resident across graph replays;
// NT loads were forcing HBM on every replay.

#define DIM 1024
#define HID 16

typedef float fvec4 __attribute__((ext_vector_type(4)));

__global__ __launch_bounds__(256) void qz_kernel(
    const float* __restrict__ x,
    const float* __restrict__ rx0,
    const float* __restrict__ ry0,
    const float* __restrict__ ry1,
    float* __restrict__ out,
    int nSamples)
{
    const int gtid = blockIdx.x * blockDim.x + threadIdx.x;
    const int wave = gtid >> 6;          // one wave64 per 4 samples
    const int lane = threadIdx.x & 63;
    const int g    = lane >> 4;          // 16-lane group -> sample index
    const int l    = lane & 15;
    const int s    = wave * 4 + g;
    if (s >= nSamples) return;

    // wave-uniform coefficients
    const float a  = ry0[0] + ry1[0];
    const float b  = rx0[0];
    const float c00  = __cosf(a) * __cosf(b);   // b00 (= -b11)
    const float tb01 = -2.0f * __sinf(a);       // 2*Re(b01)

    const fvec4* r = (const fvec4*)(x + (size_t)s * DIM);  // 256 fvec4 per row

    float s00 = 0.f, s11 = 0.f, s01 = 0.f;

    // batch A: pairs 0..3 (first-half t, second-half t)
    {
        fvec4 a0 = r[      l], a1 = r[ 16 + l], a2 = r[ 32 + l], a3 = r[ 48 + l];
        fvec4 b0 = r[128 + l], b1 = r[144 + l], b2 = r[160 + l], b3 = r[176 + l];
        s00 += a0.x*a0.x + a0.y*a0.y + a0.z*a0.z + a0.w*a0.w
             + a1.x*a1.x + a1.y*a1.y + a1.z*a1.z + a1.w*a1.w
             + a2.x*a2.x + a2.y*a2.y + a2.z*a2.z + a2.w*a2.w
             + a3.x*a3.x + a3.y*a3.y + a3.z*a3.z + a3.w*a3.w;
        s11 += b0.x*b0.x + b0.y*b0.y + b0.z*b0.z + b0.w*b0.w
             + b1.x*b1.x + b1.y*b1.y + b1.z*b1.z + b1.w*b1.w
             + b2.x*b2.x + b2.y*b2.y + b2.z*b2.z + b2.w*b2.w
             + b3.x*b3.x + b3.y*b3.y + b3.z*b3.z + b3.w*b3.w;
        s01 += a0.x*b0.x + a0.y*b0.y + a0.z*b0.z + a0.w*b0.w
             + a1.x*b1.x + a1.y*b1.y + a1.z*b1.z + a1.w*b1.w
             + a2.x*b2.x + a2.y*b2.y + a2.z*b2.z + a2.w*b2.w
             + a3.x*b3.x + a3.y*b3.y + a3.z*b3.z + a3.w*b3.w;
    }
    // batch B: pairs 4..7
    {
        fvec4 a0 = r[ 64 + l], a1 = r[ 80 + l], a2 = r[ 96 + l], a3 = r[112 + l];
        fvec4 b0 = r[192 + l], b1 = r[208 + l], b2 = r[224 + l], b3 = r[240 + l];
        s00 += a0.x*a0.x + a0.y*a0.y + a0.z*a0.z + a0.w*a0.w
             + a1.x*a1.x + a1.y*a1.y + a1.z*a1.z + a1.w*a1.w
             + a2.x*a2.x + a2.y*a2.y + a2.z*a2.z + a2.w*a2.w
             + a3.x*a3.x + a3.y*a3.y + a3.z*a3.z + a3.w*a3.w;
        s11 += b0.x*b0.x + b0.y*b0.y + b0.z*b0.z + b0.w*b0.w
             + b1.x*b1.x + b1.y*b1.y + b1.z*b1.z + b1.w*b1.w
             + b2.x*b2.x + b2.y*b2.y + b2.z*b2.z + b2.w*b2.w
             + b3.x*b3.x + b3.y*b3.y + b3.z*b3.z + b3.w*b3.w;
        s01 += a0.x*b0.x + a0.y*b0.y + a0.z*b0.z + a0.w*b0.w
             + a1.x*b1.x + a1.y*b1.y + a1.z*b1.z + a1.w*b1.w
             + a2.x*b2.x + a2.y*b2.y + a2.z*b2.z + a2.w*b2.w
             + a3.x*b3.x + a3.y*b3.y + a3.z*b3.z + a3.w*b3.w;
    }

    float num = c00 * (s00 - s11) + tb01 * s01;
    float den = s00 + s11;

    // butterfly reduce within each 16-lane group (offsets < 16 stay in-group)
    #pragma unroll
    for (int off = 8; off > 0; off >>= 1) {
        num += __shfl_xor(num, off, 64);
        den += __shfl_xor(den, off, 64);
    }

    const float z = num / den;

    // one fully-coalesced 256B store per wave: lane writes out[wave*64 + lane]
    out[(size_t)wave * 64 + lane] = z;
}

extern "C" void kernel_launch(void* const* d_in, const int* in_sizes, int n_in,
                              void* d_out, int out_size, void* d_ws, size_t ws_size,
                              hipStream_t stream) {
    const float* x   = (const float*)d_in[0];
    const float* rx0 = (const float*)d_in[1];
    const float* ry0 = (const float*)d_in[2];
    const float* ry1 = (const float*)d_in[3];
    float* out = (float*)d_out;

    const int nSamples = in_sizes[0] / DIM;                 // 16384
    const int samplesPerBlock = 16;                         // 4 waves * 4 samples
    const int blocks = (nSamples + samplesPerBlock - 1) / samplesPerBlock;

    qz_kernel<<<blocks, 256, 0, stream>>>(x, rx0, ry0, ry1, out, nSamples);
}

// Round 5
// 15.381 us; speedup vs baseline: 1.0794x; 1.0794x over previous
//
#include <hip/hip_runtime.h>

// Analytic collapse of the quantum circuit:
//   z = [cos(a)cos(b)*(S00 - S11) - 2*sin(a)*S01] / (S00 + S11)
// with a = ry0[0]+ry1[0], b = rx0[0],
//   S00 = sum(x[0:512]^2), S11 = sum(x[512:1024]^2), S01 = sum(x[0:512]*x[512:1024])
// Output: z replicated 16x per sample.
//
// R5: 4 samples/wave, 16 NT loads in flight (each a full-wave contiguous
// 1024B block from ONE row — optimal coalescing), per-row num/den computed
// per-lane, then a 2-step xor16/xor32 redistribution hands row g's partials
// to 16-lane group g (6 shfls), 4-step within-group butterfly (8 shfls).
// 3.5 cross-lane ops/sample vs R2's 12. Coalesced 256B store per wave.
// NT loads kept: harness's 268MB fills between replays evict x from L3.

#define DIM 1024
#define HID 16

typedef float fvec4 __attribute__((ext_vector_type(4)));

__device__ __forceinline__ float dot4(fvec4 a, fvec4 b) {
    return a.x*b.x + a.y*b.y + a.z*b.z + a.w*b.w;
}

__global__ __launch_bounds__(256) void qz_kernel(
    const float* __restrict__ x,
    const float* __restrict__ rx0,
    const float* __restrict__ ry0,
    const float* __restrict__ ry1,
    float* __restrict__ out,
    int nSamples)
{
    const int gtid = blockIdx.x * blockDim.x + threadIdx.x;
    const int wave = gtid >> 6;          // one wave64 per 4 samples
    const int lane = threadIdx.x & 63;
    const int s0 = wave * 4;
    if (s0 >= nSamples) return;

    // wave-uniform coefficients
    const float a  = ry0[0] + ry1[0];
    const float b  = rx0[0];
    const float c00  = __cosf(a) * __cosf(b);   // b00 (= -b11)
    const float tb01 = -2.0f * __sinf(a);       // 2*Re(b01)

    const fvec4* r0 = (const fvec4*)(x + (size_t)(s0 + 0) * DIM);
    const fvec4* r1 = (const fvec4*)(x + (size_t)(s0 + 1) * DIM);
    const fvec4* r2 = (const fvec4*)(x + (size_t)(s0 + 2) * DIM);
    const fvec4* r3 = (const fvec4*)(x + (size_t)(s0 + 3) * DIM);

    // 16 loads issued up front; each is one contiguous 1024B wave access.
    fvec4 A0 = __builtin_nontemporal_load(&r0[       lane]);
    fvec4 B0 = __builtin_nontemporal_load(&r0[ 64 + lane]);
    fvec4 C0 = __builtin_nontemporal_load(&r0[128 + lane]);
    fvec4 D0 = __builtin_nontemporal_load(&r0[192 + lane]);
    fvec4 A1 = __builtin_nontemporal_load(&r1[       lane]);
    fvec4 B1 = __builtin_nontemporal_load(&r1[ 64 + lane]);
    fvec4 C1 = __builtin_nontemporal_load(&r1[128 + lane]);
    fvec4 D1 = __builtin_nontemporal_load(&r1[192 + lane]);
    fvec4 A2 = __builtin_nontemporal_load(&r2[       lane]);
    fvec4 B2 = __builtin_nontemporal_load(&r2[ 64 + lane]);
    fvec4 C2 = __builtin_nontemporal_load(&r2[128 + lane]);
    fvec4 D2 = __builtin_nontemporal_load(&r2[192 + lane]);
    fvec4 A3 = __builtin_nontemporal_load(&r3[       lane]);
    fvec4 B3 = __builtin_nontemporal_load(&r3[ 64 + lane]);
    fvec4 C3 = __builtin_nontemporal_load(&r3[128 + lane]);
    fvec4 D3 = __builtin_nontemporal_load(&r3[192 + lane]);

    // per-row per-lane partial num/den (coefficients folded in pre-reduce)
    float s00, s11, s01;
    s00 = dot4(A0,A0) + dot4(B0,B0);  s11 = dot4(C0,C0) + dot4(D0,D0);
    s01 = dot4(A0,C0) + dot4(B0,D0);
    float n0 = c00 * (s00 - s11) + tb01 * s01, d0 = s00 + s11;

    s00 = dot4(A1,A1) + dot4(B1,B1);  s11 = dot4(C1,C1) + dot4(D1,D1);
    s01 = dot4(A1,C1) + dot4(B1,D1);
    float n1 = c00 * (s00 - s11) + tb01 * s01, d1 = s00 + s11;

    s00 = dot4(A2,A2) + dot4(B2,B2);  s11 = dot4(C2,C2) + dot4(D2,D2);
    s01 = dot4(A2,C2) + dot4(B2,D2);
    float n2 = c00 * (s00 - s11) + tb01 * s01, d2 = s00 + s11;

    s00 = dot4(A3,A3) + dot4(B3,B3);  s11 = dot4(C3,C3) + dot4(D3,D3);
    s01 = dot4(A3,C3) + dot4(B3,D3);
    float n3 = c00 * (s00 - s11) + tb01 * s01, d3 = s00 + s11;

    // redistribution step 1 (xor 16): keep rows with (row&1)==(g&1)
    const bool odd = (lane & 16) != 0;
    float kAn = odd ? n1 : n0, sAn = odd ? n0 : n1;
    float kAd = odd ? d1 : d0, sAd = odd ? d0 : d1;
    float kBn = odd ? n3 : n2, sBn = odd ? n2 : n3;
    float kBd = odd ? d3 : d2, sBd = odd ? d2 : d3;
    float nA = kAn + __shfl_xor(sAn, 16, 64);   // row (g&1)
    float dA = kAd + __shfl_xor(sAd, 16, 64);
    float nB = kBn + __shfl_xor(sBn, 16, 64);   // row (g&1)+2
    float dB = kBd + __shfl_xor(sBd, 16, 64);

    // redistribution step 2 (xor 32): keep row with (row&2)==(g&2) -> row g
    const bool two = (lane & 32) != 0;
    float kn = two ? nB : nA, sn = two ? nA : nB;
    float kd = two ? dB : dA, sd = two ? dA : dB;
    float n = kn + __shfl_xor(sn, 32, 64);
    float d = kd + __shfl_xor(sd, 32, 64);

    // within-16-lane butterfly: group g now fully reduces row g
    #pragma unroll
    for (int off = 8; off > 0; off >>= 1) {
        n += __shfl_xor(n, off, 64);
        d += __shfl_xor(d, off, 64);
    }

    const float z = n / d;

    // coalesced 256B store: lane writes out[wave*64 + lane]
    // (sample wave*4+g occupies out[.. + g*16 .. g*16+15], lane = g*16+l)
    out[(size_t)wave * 64 + lane] = z;
}

extern "C" void kernel_launch(void* const* d_in, const int* in_sizes, int n_in,
                              void* d_out, int out_size, void* d_ws, size_t ws_size,
                              hipStream_t stream) {
    const float* x   = (const float*)d_in[0];
    const float* rx0 = (const float*)d_in[1];
    const float* ry0 = (const float*)d_in[2];
    const float* ry1 = (const float*)d_in[3];
    float* out = (float*)d_out;

    const int nSamples = in_sizes[0] / DIM;                 // 16384
    const int samplesPerBlock = 16;                         // 4 waves * 4 samples
    const int blocks = (nSamples + samplesPerBlock - 1) / samplesPerBlock;

    qz_kernel<<<blocks, 256, 0, stream>>>(x, rx0, ry0, ry1, out, nSamples);
}

// Round 6
// 14.276 us; speedup vs baseline: 1.1630x; 1.0774x over previous
//
#include <hip/hip_runtime.h>

// Analytic collapse of the quantum circuit:
//   z = [cos(a)cos(b)*(S00 - S11) - 2*sin(a)*S01] / (S00 + S11)
// with a = ry0[0]+ry1[0], b = rx0[0],
//   S00 = sum(x[0:512]^2), S11 = sum(x[512:1024]^2), S01 = sum(x[0:512]*x[512:1024])
// Output: z replicated 16x per sample.
//
// R6: software-pipelined pairs. Each wave handles 4 samples as 2 pairs:
// issue pair0's 8 NT loads, then pair1's 8 NT loads, compute+REDUCE pair0
// while pair1's loads are still in flight (shfl=lgkmcnt vs loads=vmcnt ->
// compiler waits only vmcnt(8) for pair0). The 6-step shfl chain is no
// longer an exposed per-wave tail. Single coalesced 256B store at the end.

#define DIM 1024
#define HID 16

typedef float fvec4 __attribute__((ext_vector_type(4)));

__device__ __forceinline__ float dot4(fvec4 a, fvec4 b) {
    return a.x*b.x + a.y*b.y + a.z*b.z + a.w*b.w;
}

__global__ __launch_bounds__(256) void qz_kernel(
    const float* __restrict__ x,
    const float* __restrict__ rx0,
    const float* __restrict__ ry0,
    const float* __restrict__ ry1,
    float* __restrict__ out,
    int nSamples)
{
    const int gtid = blockIdx.x * blockDim.x + threadIdx.x;
    const int wave = gtid >> 6;          // one wave64 per 4 samples
    const int lane = threadIdx.x & 63;
    const int s0 = wave * 4;
    if (s0 >= nSamples) return;

    const fvec4* r0 = (const fvec4*)(x + (size_t)(s0 + 0) * DIM);
    const fvec4* r1 = (const fvec4*)(x + (size_t)(s0 + 1) * DIM);
    const fvec4* r2 = (const fvec4*)(x + (size_t)(s0 + 2) * DIM);
    const fvec4* r3 = (const fvec4*)(x + (size_t)(s0 + 3) * DIM);

    // pair0 loads (rows s0, s0+1) — issued first
    fvec4 A0 = __builtin_nontemporal_load(&r0[       lane]);
    fvec4 B0 = __builtin_nontemporal_load(&r0[ 64 + lane]);
    fvec4 C0 = __builtin_nontemporal_load(&r0[128 + lane]);
    fvec4 D0 = __builtin_nontemporal_load(&r0[192 + lane]);
    fvec4 A1 = __builtin_nontemporal_load(&r1[       lane]);
    fvec4 B1 = __builtin_nontemporal_load(&r1[ 64 + lane]);
    fvec4 C1 = __builtin_nontemporal_load(&r1[128 + lane]);
    fvec4 D1 = __builtin_nontemporal_load(&r1[192 + lane]);
    // pair1 loads (rows s0+2, s0+3) — stay in flight during pair0's reduce
    fvec4 A2 = __builtin_nontemporal_load(&r2[       lane]);
    fvec4 B2 = __builtin_nontemporal_load(&r2[ 64 + lane]);
    fvec4 C2 = __builtin_nontemporal_load(&r2[128 + lane]);
    fvec4 D2 = __builtin_nontemporal_load(&r2[192 + lane]);
    fvec4 A3 = __builtin_nontemporal_load(&r3[       lane]);
    fvec4 B3 = __builtin_nontemporal_load(&r3[ 64 + lane]);
    fvec4 C3 = __builtin_nontemporal_load(&r3[128 + lane]);
    fvec4 D3 = __builtin_nontemporal_load(&r3[192 + lane]);

    // wave-uniform coefficients — computed while loads are in flight
    const float a  = ry0[0] + ry1[0];
    const float b  = rx0[0];
    const float c00  = __cosf(a) * __cosf(b);   // b00 (= -b11)
    const float tb01 = -2.0f * __sinf(a);       // 2*Re(b01)

    // ---- pair0 compute (needs only first 8 loads: vmcnt(8)) ----
    float s00, s11, s01;
    s00 = dot4(A0,A0) + dot4(B0,B0);  s11 = dot4(C0,C0) + dot4(D0,D0);
    s01 = dot4(A0,C0) + dot4(B0,D0);
    float n0 = c00 * (s00 - s11) + tb01 * s01, d0 = s00 + s11;

    s00 = dot4(A1,A1) + dot4(B1,B1);  s11 = dot4(C1,C1) + dot4(D1,D1);
    s01 = dot4(A1,C1) + dot4(B1,D1);
    float n1 = c00 * (s00 - s11) + tb01 * s01, d1 = s00 + s11;

    // pair0 reduce — overlaps pair1's outstanding loads
    #pragma unroll
    for (int off = 32; off > 0; off >>= 1) {
        n0 += __shfl_xor(n0, off, 64);
        d0 += __shfl_xor(d0, off, 64);
        n1 += __shfl_xor(n1, off, 64);
        d1 += __shfl_xor(d1, off, 64);
    }
    const float z0 = n0 / d0;
    const float z1 = n1 / d1;

    // ---- pair1 compute (vmcnt(0)) ----
    s00 = dot4(A2,A2) + dot4(B2,B2);  s11 = dot4(C2,C2) + dot4(D2,D2);
    s01 = dot4(A2,C2) + dot4(B2,D2);
    float n2 = c00 * (s00 - s11) + tb01 * s01, d2 = s00 + s11;

    s00 = dot4(A3,A3) + dot4(B3,B3);  s11 = dot4(C3,C3) + dot4(D3,D3);
    s01 = dot4(A3,C3) + dot4(B3,D3);
    float n3 = c00 * (s00 - s11) + tb01 * s01, d3 = s00 + s11;

    #pragma unroll
    for (int off = 32; off > 0; off >>= 1) {
        n2 += __shfl_xor(n2, off, 64);
        d2 += __shfl_xor(d2, off, 64);
        n3 += __shfl_xor(n3, off, 64);
        d3 += __shfl_xor(d3, off, 64);
    }
    const float z2 = n2 / d2;
    const float z3 = n3 / d3;

    // single fully-coalesced 256B store: lanes 0..15 each write one fvec4
    if (lane < 16) {
        const float zlo = (lane < 4) ? z0 : z1;
        const float zhi = (lane < 12) ? z2 : z3;
        const float z = (lane < 8) ? zlo : zhi;
        fvec4 zv = {z, z, z, z};
        fvec4* o = (fvec4*)(out + (size_t)s0 * HID);
        __builtin_nontemporal_store(zv, &o[lane]);
    }
}

extern "C" void kernel_launch(void* const* d_in, const int* in_sizes, int n_in,
                              void* d_out, int out_size, void* d_ws, size_t ws_size,
                              hipStream_t stream) {
    const float* x   = (const float*)d_in[0];
    const float* rx0 = (const float*)d_in[1];
    const float* ry0 = (const float*)d_in[2];
    const float* ry1 = (const float*)d_in[3];
    float* out = (float*)d_out;

    const int nSamples = in_sizes[0] / DIM;                 // 16384
    const int samplesPerBlock = 16;                         // 4 waves * 4 samples
    const int blocks = (nSamples + samplesPerBlock - 1) / samplesPerBlock;

    qz_kernel<<<blocks, 256, 0, stream>>>(x, rx0, ry0, ry1, out, nSamples);
}